// Round 20
// baseline (69.322 us; speedup 1.0000x reference)
//
#include <hip/hip_runtime.h>
#include <hip/hip_fp16.h>
#include <math.h>

#define N_MESH   5151
#define NB       8
#define TT       2048
#define HID      256
#define NLAYERS  3
#define NCHUNK   64
#define CHUNK    32            // TT / NCHUNK
#define NQ       11            // mesh points per thread (11*512 = 5632)
#define NPAD     5632
#define SCAN_GRID 512          // 8 b x 64 c, one block per (b,c)
#define PREP_NBLK 48           // 24576 / 512
#define COPY_NBLK 61           // 123624 / 2048 rounded up
#define MLP_NBLK  81           // 81*64 rows
#define PH2_NBLK  88           // 11 x 8
#define DENSB_NBLK 21          // 41208 / 2048 rounded up

// scan smem layout (bytes): hs2[34] @0 (pad to 144), tp[32] float4 @144
#define OFF_TP    144
#define SMEM1     656
#define OFF_RED   656          // k3: [32 t][36] floats = 4608
#define OFF_DRED  5264         // k3: [32] floats
#define SMEM3     5392

// ws layout (floats)
#define WS_DENSITY 0           // 5151
#define WS_WT      6144        // 98304 floats (24576 half8)
#define WS_PQ      104448      // NCHUNK*NB*NPAD*2 = 5767168 -> ends 5871616
#define WS_S       5871616     // NCHUNK*NB*NPAD = 2883584 -> ends 8755200 (~35MB)

// out layout (floats)
#define OUT_BNORM  0           // 16384
#define OUT_DENSB  16384       // 41208
#define OUT_M      57592       // 16384
#define OUT_S0     73976       // 41208
#define OUT_MESHB  115184      // 82416

typedef _Float16 half8  __attribute__((ext_vector_type(8)));
typedef float    f32x4  __attribute__((ext_vector_type(4)));

__device__ __forceinline__ float sigmoid_fast(float x) {
    float e = __expf(-x);
    return __builtin_amdgcn_rcpf(1.0f + e);
}

// clamp-to-[0,1] that folds into the producing VALU op's clamp modifier
__device__ __forceinline__ float sat01(float x) {
    return __builtin_fmaxf(__builtin_fminf(x, 1.0f), 0.0f);
}

// hA byte offset with XOR swizzle (row stride 512 B fp16) -- MLP only
__device__ __forceinline__ int swz(int row, int kbyte) {
    return row * 512 + (kbyte ^ ((row & 7) << 4));
}

// 16-lane sum via DPP (VALU pipe, zero DS ops)
__device__ __forceinline__ float dpp16_sum(float v) {
    int a;
    a = __builtin_amdgcn_update_dpp(0, __float_as_int(v), 0xB1, 0xF, 0xF, true);
    v += __int_as_float(a);
    a = __builtin_amdgcn_update_dpp(0, __float_as_int(v), 0x4E, 0xF, 0xF, true);
    v += __int_as_float(a);
    a = __builtin_amdgcn_update_dpp(0, __float_as_int(v), 0x141, 0xF, 0xF, true);
    v += __int_as_float(a);
    a = __builtin_amdgcn_update_dpp(0, __float_as_int(v), 0x140, 0xF, 0xF, true);
    v += __int_as_float(a);
    return v;
}

// Per-t wave-uniform params: {dl, u, v, sg}.
// inc: A = sat(g + v); dec: A = sat(v - g)
__device__ __forceinline__ void build_params(int tid, const float* hs2,
                                             float4* tp)
{
    if (tid < CHUNK) {
        float ht = hs2[tid + 1];
        float hp = hs2[tid];
        bool inc = (ht >= hp);
        float sg = inc ? 1.f : -1.f;
        float psg = sg;
        if (tid > 0) psg = (hs2[tid] >= hs2[tid - 1]) ? 1.f : -1.f;
        float x = ht * 1000.f;
        float gc = rintf(ht * 100.f);
        float4 p;
        p.x = psg - sg;                       // dl (0 or +-2)
        if (inc) {
            float Ac = sigmoid_fast(fmaf(10.f, gc, -x));
            p.y = 1.f;  p.z = Ac - gc;
        } else {
            float Ac = sigmoid_fast(fmaf(-10.f, gc, x));
            p.y = -1.f; p.z = gc + Ac;
        }
        p.w = sg;
        tp[tid] = p;
    }
}

// ---------------------------------------------------------------------------
// k1: blocks [0,512) phase1; [512,560) W prep; [560,621) s0/mesh_b copies.
// ---------------------------------------------------------------------------
__global__ __launch_bounds__(512, 4) void k1_scan1_prep(
    const float* __restrict__ dec, const float* __restrict__ y0,
    const float* __restrict__ mesh, const float* __restrict__ Wblk,
    float2* __restrict__ PQ, half8* __restrict__ WT,
    const float* __restrict__ s0, float* __restrict__ out)
{
    __shared__ __align__(16) char smem[SMEM1];
    const int tid = threadIdx.x;
    const int bid = blockIdx.x;

    if (bid >= SCAN_GRID + PREP_NBLK) {
        // ---- s0 / mesh_b copies ----
        int idx = bid - (SCAN_GRID + PREP_NBLK);
        const int n1 = NB * N_MESH;                 // 41208
        const int total = 3 * n1;                   // 123624
#pragma unroll
        for (int k = 0; k < 4; ++k) {
            int j = idx * 2048 + k * 512 + tid;
            if (j < total) {
                if (j < n1) out[OUT_S0 + j] = s0[j];
                else {
                    int jj = j - n1;
                    out[OUT_MESHB + jj] = mesh[jj % (2 * N_MESH)];
                }
            }
        }
        return;
    }

    if (bid >= SCAN_GRID) {
        // ---- prep: gather W into per-lane MFMA fragment order ----
        int g = (bid - SCAN_GRID) * 512 + tid;   // [0, 24576)
        int l  = g & 63;
        int nt = (g >> 6) & 15;
        int kg = (g >> 10) & 7;
        int L  = g >> 13;
        int n  = nt * 16 + (l & 15);
        int kb = kg * 32 + ((l >> 4) & 3) * 8;
        const float* Wb = Wblk + (size_t)L * HID * HID;
        half8 v;
#pragma unroll
        for (int i = 0; i < 8; ++i)
            v[i] = (_Float16)Wb[(size_t)(kb + i) * HID + n];
        WT[g] = v;
        return;
    }

    // ---- phase1 ----
    float* hs2 = (float*)smem;
    float4* tp = (float4*)(smem + OFF_TP);

    const int b = bid & 7;
    const int c = bid >> 3;
    const int t0 = c * CHUNK;

    if (tid < CHUNK) hs2[tid + 1] = dec[b * TT + t0 + tid];
    if (tid == 0) hs2[0] = (c == 0) ? y0[b] : dec[b * TT + t0 - 1];

    float fga[NQ], fgb[NQ];
#pragma unroll
    for (int q = 0; q < NQ; ++q) {
        int n = q * 512 + tid;
        if (n < N_MESH) {
            float2 mv = *(const float2*)&mesh[2 * n];
            fgb[q] = rintf(mv.x * 100.0f);
            fga[q] = rintf(mv.y * 100.0f);
        } else { fga[q] = 0.f; fgb[q] = 0.f; }
    }
    __syncthreads();
    build_params(tid, hs2, tp);
    __syncthreads();

    float P[NQ], R[NQ];
    float sg0 = tp[0].w;
#pragma unroll
    for (int q = 0; q < NQ; ++q) { P[q] = 1.f; R[q] = -sg0; }

    for (int tb = 0; tb < CHUNK; tb += 8) {
#pragma unroll
        for (int j = 0; j < 8; ++j) {
            float4 p = tp[tb + j];
            bool inc = p.y > 0.f;
            bool dl0 = p.x == 0.f;
            if (inc) {
                if (dl0) {
#pragma unroll
                    for (int q = 0; q < NQ; ++q) {
                        float A = sat01(fga[q] + p.z);
                        P[q] *= A;
                        R[q] *= A;
                    }
                } else {
#pragma unroll
                    for (int q = 0; q < NQ; ++q) {
                        float A = sat01(fga[q] + p.z);
                        P[q] *= A;
                        R[q] = (R[q] + p.x) * A;
                    }
                }
            } else {
                if (dl0) {
#pragma unroll
                    for (int q = 0; q < NQ; ++q) {
                        float A = sat01(p.z - fgb[q]);
                        P[q] *= A;
                        R[q] *= A;
                    }
                } else {
#pragma unroll
                    for (int q = 0; q < NQ; ++q) {
                        float A = sat01(p.z - fgb[q]);
                        P[q] *= A;
                        R[q] = (R[q] + p.x) * A;
                    }
                }
            }
        }
    }
    float sgl = tp[CHUNK - 1].w;
    size_t basew = ((size_t)(c * NB + b)) * NPAD;
#pragma unroll
    for (int q = 0; q < NQ; ++q) {
        float2 v; v.x = P[q]; v.y = R[q] + sgl;
        PQ[basew + q * 512 + tid] = v;
    }
}

// ---------------------------------------------------------------------------
// k2: blocks [0,81) = MFMA density MLP (proven body); [81,169) = phase2.
// ---------------------------------------------------------------------------
__global__ __launch_bounds__(512) void k2_mlp_phase2(
    const float* __restrict__ mesh, const float* __restrict__ Win,
    const float* __restrict__ bin,  const half8* __restrict__ WT,
    const float* __restrict__ bblk, const float* __restrict__ Wout,
    const float* __restrict__ bout, float* __restrict__ density,
    const float* __restrict__ s0_in, const float2* __restrict__ PQ,
    float* __restrict__ Sarr)
{
    __shared__ __align__(16) char hA[64 * 512];   // 32 KB
    __shared__ float psum[4][16][2];
    const int tid  = threadIdx.x;

    if (blockIdx.x >= MLP_NBLK) {
        // ---- phase2: boundary states into dense Sarr ----
        int idx = blockIdx.x - MLP_NBLK;   // 0..87
        int nbb = idx % NQ;
        int b   = idx / NQ;
        int n   = nbb * 512 + tid;
        float s = (n < N_MESH) ? s0_in[b * N_MESH + n] : 0.f;
#pragma unroll 4
        for (int c = 0; c < NCHUNK; ++c) {
            size_t ix = ((size_t)(c * NB + b)) * NPAD + n;
            float2 pv = PQ[ix];
            Sarr[ix] = s;
            s = fmaf(pv.x, s, pv.y);
        }
        return;
    }

    const int w    = tid >> 6;
    const int lane = tid & 63;
    const int rl   = lane & 15;
    const int cg   = lane >> 4;
    const int mt   = w & 3;
    const int nh   = w >> 2;
    const int row0 = blockIdx.x * 64;

    float hreg[8][4];

    {
        float m0[4], m1[4];
#pragma unroll
        for (int r = 0; r < 4; ++r) {
            int gr = row0 + mt * 16 + cg * 4 + r;
            if (gr < N_MESH) { m0[r] = mesh[2 * gr]; m1[r] = mesh[2 * gr + 1]; }
            else { m0[r] = 0.f; m1[r] = 0.f; }
        }
#pragma unroll
        for (int j = 0; j < 8; ++j) {
            int col = nh * 128 + j * 16 + rl;
            float wa = Win[col], wb = Win[HID + col], bi = bin[col];
#pragma unroll
            for (int r = 0; r < 4; ++r) {
                float v = fmaxf(fmaf(m0[r], wa, fmaf(m1[r], wb, bi)), 0.f);
                hreg[j][r] = v;
                *(_Float16*)(hA + swz(mt * 16 + cg * 4 + r, col * 2)) =
                    (_Float16)v;
            }
        }
    }
    __syncthreads();

    for (int L = 0; L < NLAYERS; ++L) {
        half8 af[8];
#pragma unroll
        for (int kg = 0; kg < 8; ++kg)
            af[kg] = *(const half8*)(hA + swz(mt * 16 + rl, kg * 64 + cg * 16));
        __syncthreads();

        float bias[8];
#pragma unroll
        for (int j = 0; j < 8; ++j)
            bias[j] = bblk[L * HID + nh * 128 + j * 16 + rl];

        f32x4 acc[8];
#pragma unroll
        for (int j = 0; j < 8; ++j) acc[j] = (f32x4){0.f, 0.f, 0.f, 0.f};

        const half8* WTL = WT + ((size_t)(L * 8) * 16 + nh * 8) * 64 + lane;
        half8 b0[8], b1[8];
#pragma unroll
        for (int j = 0; j < 8; ++j) b0[j] = WTL[(size_t)j * 64];
#pragma unroll
        for (int kg2 = 0; kg2 < 8; kg2 += 2) {
#pragma unroll
            for (int j = 0; j < 8; ++j)
                b1[j] = WTL[(size_t)(kg2 + 1) * 1024 + (size_t)j * 64];
#pragma unroll
            for (int j = 0; j < 8; ++j)
                acc[j] = __builtin_amdgcn_mfma_f32_16x16x32_f16(
                    af[kg2], b0[j], acc[j], 0, 0, 0);
            if (kg2 + 2 < 8) {
#pragma unroll
                for (int j = 0; j < 8; ++j)
                    b0[j] = WTL[(size_t)(kg2 + 2) * 1024 + (size_t)j * 64];
            }
#pragma unroll
            for (int j = 0; j < 8; ++j)
                acc[j] = __builtin_amdgcn_mfma_f32_16x16x32_f16(
                    af[kg2 + 1], b1[j], acc[j], 0, 0, 0);
        }

#pragma unroll
        for (int j = 0; j < 8; ++j) {
            int col = nh * 128 + j * 16 + rl;
#pragma unroll
            for (int r = 0; r < 4; ++r) {
                float v = hreg[j][r] + fmaxf(acc[j][r] + bias[j], 0.f);
                hreg[j][r] = v;
                if (L < NLAYERS - 1)
                    *(_Float16*)(hA + swz(mt * 16 + cg * 4 + r, col * 2)) =
                        (_Float16)v;
            }
        }
        if (L < NLAYERS - 1) __syncthreads();
    }

    {
        float p[4] = {0.f, 0.f, 0.f, 0.f};
#pragma unroll
        for (int j = 0; j < 8; ++j) {
            float wo = Wout[nh * 128 + j * 16 + rl];
#pragma unroll
            for (int r = 0; r < 4; ++r) p[r] = fmaf(hreg[j][r], wo, p[r]);
        }
#pragma unroll
        for (int st = 1; st < 16; st <<= 1)
#pragma unroll
            for (int r = 0; r < 4; ++r) p[r] += __shfl_xor(p[r], st, 64);
        if (rl == 0) {
#pragma unroll
            for (int r = 0; r < 4; ++r) psum[mt][cg * 4 + r][nh] = p[r];
        }
    }
    __syncthreads();
    if (tid < 64) {
        int gr = row0 + tid;
        float pp = psum[tid >> 4][tid & 15][0] + psum[tid >> 4][tid & 15][1];
        if (gr < N_MESH) density[gr] = sigmoid_fast(pp + bout[0]);
    }
}

// ---------------------------------------------------------------------------
// k3: blocks [0,512) phase3 + in-block finalize; [512,533) density_b copy.
// ---------------------------------------------------------------------------
__global__ __launch_bounds__(512, 4) void k3_phase3_fin(
    const float* __restrict__ dec, const float* __restrict__ y0,
    const float* __restrict__ mesh, const float* __restrict__ density,
    const float* __restrict__ Sarr, float* __restrict__ out)
{
    __shared__ __align__(16) char smem[SMEM3];
    const int tid = threadIdx.x;
    const int bid = blockIdx.x;

    if (bid >= SCAN_GRID) {
        // ---- density_b copy ----
        int idx = bid - SCAN_GRID;
#pragma unroll
        for (int k = 0; k < 4; ++k) {
            int j = idx * 2048 + k * 512 + tid;
            if (j < NB * N_MESH) out[OUT_DENSB + j] = density[j % N_MESH];
        }
        return;
    }

    float* hs2 = (float*)smem;
    float4* tp = (float4*)(smem + OFF_TP);
    float* red  = (float*)(smem + OFF_RED);    // [32 t][36]
    float* Dred = (float*)(smem + OFF_DRED);   // [32]

    const int b = bid & 7;
    const int c = bid >> 3;
    const int t0 = c * CHUNK;

    if (tid < CHUNK) hs2[tid + 1] = dec[b * TT + t0 + tid];
    if (tid == 0) hs2[0] = (c == 0) ? y0[b] : dec[b * TT + t0 - 1];

    float fga[NQ], fgb[NQ];
    float d[NQ], S[NQ];
#pragma unroll
    for (int q = 0; q < NQ; ++q) {
        int n = q * 512 + tid;
        if (n < N_MESH) {
            float2 mv = *(const float2*)&mesh[2 * n];
            fgb[q] = rintf(mv.x * 100.0f);
            fga[q] = rintf(mv.y * 100.0f);
            d[q]  = density[n];
            S[q]  = Sarr[((size_t)(c * NB + b)) * NPAD + n];
        } else { fga[q] = 0.f; fgb[q] = 0.f; d[q] = 0.f; S[q] = 0.f; }
    }
    // block-local D = sum(density) (identical order in every block)
    {
        float Dp = 0.f;
#pragma unroll
        for (int q = 0; q < NQ; ++q) Dp += d[q];
        Dp = dpp16_sum(Dp);
        if ((tid & 15) == 0) Dred[tid >> 4] = Dp;
    }
    __syncthreads();
    build_params(tid, hs2, tp);
    __syncthreads();

    float z[NQ];
    float sg0 = tp[0].w;
#pragma unroll
    for (int q = 0; q < NQ; ++q) z[q] = S[q] - sg0;

    for (int tb = 0; tb < CHUNK; tb += 8) {
        float v[8];
#pragma unroll
        for (int j = 0; j < 8; ++j) {
            float4 p = tp[tb + j];
            bool inc = p.y > 0.f;
            bool dl0 = p.x == 0.f;
            float a0 = 0.f, a1 = 0.f;
            if (inc) {
                if (dl0) {
#pragma unroll
                    for (int q = 0; q < NQ; ++q) {
                        float A = sat01(fga[q] + p.z);
                        float zn = z[q] * A;
                        z[q] = zn;
                        if (q & 1) a1 = fmaf(d[q], zn, a1);
                        else       a0 = fmaf(d[q], zn, a0);
                    }
                } else {
#pragma unroll
                    for (int q = 0; q < NQ; ++q) {
                        float A = sat01(fga[q] + p.z);
                        float zn = (z[q] + p.x) * A;
                        z[q] = zn;
                        if (q & 1) a1 = fmaf(d[q], zn, a1);
                        else       a0 = fmaf(d[q], zn, a0);
                    }
                }
            } else {
                if (dl0) {
#pragma unroll
                    for (int q = 0; q < NQ; ++q) {
                        float A = sat01(p.z - fgb[q]);
                        float zn = z[q] * A;
                        z[q] = zn;
                        if (q & 1) a1 = fmaf(d[q], zn, a1);
                        else       a0 = fmaf(d[q], zn, a0);
                    }
                } else {
#pragma unroll
                    for (int q = 0; q < NQ; ++q) {
                        float A = sat01(p.z - fgb[q]);
                        float zn = (z[q] + p.x) * A;
                        z[q] = zn;
                        if (q & 1) a1 = fmaf(d[q], zn, a1);
                        else       a0 = fmaf(d[q], zn, a0);
                    }
                }
            }
            v[j] = a0 + a1;
        }
#pragma unroll
        for (int j = 0; j < 8; ++j) v[j] = dpp16_sum(v[j]);
        float outv = v[0];
#pragma unroll
        for (int j = 1; j < 8; ++j) if ((tid & 15) == j) outv = v[j];
        if ((tid & 15) < 8)
            red[(tb + (tid & 15)) * 36 + (tid >> 4)] = outv;
    }
    __syncthreads();

    // finalize: 32 threads, one per t in this chunk
    if (tid < CHUNK) {
        float acc = 0.f;
#pragma unroll
        for (int g4 = 0; g4 < 32; g4 += 4) {
            float4 r4 = *(const float4*)&red[tid * 36 + g4];
            acc += (r4.x + r4.y) + (r4.z + r4.w);
        }
        float D = 0.f;
#pragma unroll
        for (int g4 = 0; g4 < 32; g4 += 4) {
            float4 d4 = *(const float4*)&Dred[g4];
            D += (d4.x + d4.y) + (d4.z + d4.w);
        }
        float gd = tp[tid].w;                // direction sign at t
        int t = t0 + tid;
        float m = (acc + gd * D) / D;
        out[OUT_M + b * TT + t] = m;
        out[OUT_BNORM + b * TT + t] = 0.5f * m + 0.5f;
    }
}

extern "C" void kernel_launch(void* const* d_in, const int* in_sizes, int n_in,
                              void* d_out, int out_size, void* d_ws, size_t ws_size,
                              hipStream_t stream) {
    const float* dec  = (const float*)d_in[1];
    const float* s0   = (const float*)d_in[2];
    const float* y0   = (const float*)d_in[3];
    const float* mesh = (const float*)d_in[4];
    const float* Win  = (const float*)d_in[5];
    const float* bin  = (const float*)d_in[6];
    const float* Wblk = (const float*)d_in[7];
    const float* bblk = (const float*)d_in[8];
    const float* Wout = (const float*)d_in[9];
    const float* bout = (const float*)d_in[10];
    float* out = (float*)d_out;
    float* ws  = (float*)d_ws;

    float*  density  = ws + WS_DENSITY;
    half8*  wt       = (half8*)(ws + WS_WT);
    float*  pqf      = ws + WS_PQ;
    float2* pq       = (float2*)pqf;
    float*  sarr     = ws + WS_S;

    k1_scan1_prep<<<SCAN_GRID + PREP_NBLK + COPY_NBLK, 512, 0, stream>>>(
        dec, y0, mesh, Wblk, pq, wt, s0, out);
    k2_mlp_phase2<<<MLP_NBLK + PH2_NBLK, 512, 0, stream>>>(
        mesh, Win, bin, wt, bblk, Wout, bout, density, s0, pq, sarr);
    k3_phase3_fin<<<SCAN_GRID + DENSB_NBLK, 512, 0, stream>>>(
        dec, y0, mesh, density, sarr, out);
}

// Round 21
// 61.066 us; speedup vs baseline: 1.1352x; 1.1352x over previous
//
#include <hip/hip_runtime.h>
#include <hip/hip_fp16.h>
#include <math.h>

#define N_MESH   5151
#define NB       8
#define TT       2048
#define HID      256
#define NLAYERS  3
#define NCHUNK   64
#define CHUNK    32            // TT / NCHUNK
#define NQ       11            // mesh points per thread (11*512 = 5632)
#define NPAD     5632
#define SCAN_GRID 512          // 8 b x 64 c, one block per (b,c)
#define PREP_NBLK 48           // 24576 / 512
#define COPY_NBLK 61           // 123624 / 2048 rounded up
#define MLP_NBLK  81           // 81*64 rows
#define PH2_NBLK  88           // 11 x 8
#define DENSB_NBLK 21          // 41208 / 2048 rounded up

// scan smem layout (bytes): hs2[34] @0 (pad to 144), tp[32] float4 @144
#define OFF_TP    144
#define SMEM1     656
#define OFF_RED   656          // k3: [32 t][36] floats = 4608
#define OFF_DRED  5264         // k3: [32] floats
#define SMEM3     5392

// ws layout (floats)
#define WS_DENSITY 0           // 5151
#define WS_WT      6144        // 98304 floats (24576 half8)
#define WS_PQ      104448      // NCHUNK*NB*NPAD*2 = 5767168 -> ends 5871616
#define WS_S       5871616     // NCHUNK*NB*NPAD = 2883584 -> ends 8755200 (~35MB)

// out layout (floats)
#define OUT_BNORM  0           // 16384
#define OUT_DENSB  16384       // 41208
#define OUT_M      57592       // 16384
#define OUT_S0     73976       // 41208
#define OUT_MESHB  115184      // 82416

typedef _Float16 half8  __attribute__((ext_vector_type(8)));
typedef float    f32x4  __attribute__((ext_vector_type(4)));

__device__ __forceinline__ float sigmoid_fast(float x) {
    float e = __expf(-x);
    return __builtin_amdgcn_rcpf(1.0f + e);
}

// hA byte offset with XOR swizzle (row stride 512 B fp16) -- MLP only
__device__ __forceinline__ int swz(int row, int kbyte) {
    return row * 512 + (kbyte ^ ((row & 7) << 4));
}

// 16-lane sum via DPP (VALU pipe, zero DS ops)
__device__ __forceinline__ float dpp16_sum(float v) {
    int a;
    a = __builtin_amdgcn_update_dpp(0, __float_as_int(v), 0xB1, 0xF, 0xF, true);
    v += __int_as_float(a);
    a = __builtin_amdgcn_update_dpp(0, __float_as_int(v), 0x4E, 0xF, 0xF, true);
    v += __int_as_float(a);
    a = __builtin_amdgcn_update_dpp(0, __float_as_int(v), 0x141, 0xF, 0xF, true);
    v += __int_as_float(a);
    a = __builtin_amdgcn_update_dpp(0, __float_as_int(v), 0x140, 0xF, 0xF, true);
    v += __int_as_float(a);
    return v;
}

// Per-t wave-uniform params: {dl, u, v, sg}.
// inc: A = med3(g + v, 0, 1); dec: A = med3(v - g, 0, 1)
__device__ __forceinline__ void build_params(int tid, const float* hs2,
                                             float4* tp)
{
    if (tid < CHUNK) {
        float ht = hs2[tid + 1];
        float hp = hs2[tid];
        bool inc = (ht >= hp);
        float sg = inc ? 1.f : -1.f;
        float psg = sg;
        if (tid > 0) psg = (hs2[tid] >= hs2[tid - 1]) ? 1.f : -1.f;
        float x = ht * 1000.f;
        float gc = rintf(ht * 100.f);
        float4 p;
        p.x = psg - sg;                       // dl (0 or +-2)
        if (inc) {
            float Ac = sigmoid_fast(fmaf(10.f, gc, -x));
            p.y = 1.f;  p.z = Ac - gc;
        } else {
            float Ac = sigmoid_fast(fmaf(-10.f, gc, x));
            p.y = -1.f; p.z = gc + Ac;
        }
        p.w = sg;
        tp[tid] = p;
    }
}

// ---------------------------------------------------------------------------
// k1: blocks [0,512) phase1; [512,560) W prep; [560,621) s0/mesh_b copies.
// ---------------------------------------------------------------------------
__global__ __launch_bounds__(512, 4) void k1_scan1_prep(
    const float* __restrict__ dec, const float* __restrict__ y0,
    const float* __restrict__ mesh, const float* __restrict__ Wblk,
    float2* __restrict__ PQ, half8* __restrict__ WT,
    const float* __restrict__ s0, float* __restrict__ out)
{
    __shared__ __align__(16) char smem[SMEM1];
    const int tid = threadIdx.x;
    const int bid = blockIdx.x;

    if (bid >= SCAN_GRID + PREP_NBLK) {
        // ---- s0 / mesh_b copies ----
        int idx = bid - (SCAN_GRID + PREP_NBLK);
        const int n1 = NB * N_MESH;                 // 41208
        const int total = 3 * n1;                   // 123624
#pragma unroll
        for (int k = 0; k < 4; ++k) {
            int j = idx * 2048 + k * 512 + tid;
            if (j < total) {
                if (j < n1) out[OUT_S0 + j] = s0[j];
                else {
                    int jj = j - n1;
                    out[OUT_MESHB + jj] = mesh[jj % (2 * N_MESH)];
                }
            }
        }
        return;
    }

    if (bid >= SCAN_GRID) {
        // ---- prep: gather W into per-lane MFMA fragment order ----
        int g = (bid - SCAN_GRID) * 512 + tid;   // [0, 24576)
        int l  = g & 63;
        int nt = (g >> 6) & 15;
        int kg = (g >> 10) & 7;
        int L  = g >> 13;
        int n  = nt * 16 + (l & 15);
        int kb = kg * 32 + ((l >> 4) & 3) * 8;
        const float* Wb = Wblk + (size_t)L * HID * HID;
        half8 v;
#pragma unroll
        for (int i = 0; i < 8; ++i)
            v[i] = (_Float16)Wb[(size_t)(kb + i) * HID + n];
        WT[g] = v;
        return;
    }

    // ---- phase1 ----
    float* hs2 = (float*)smem;
    float4* tp = (float4*)(smem + OFF_TP);

    const int b = bid & 7;
    const int c = bid >> 3;
    const int t0 = c * CHUNK;

    if (tid < CHUNK) hs2[tid + 1] = dec[b * TT + t0 + tid];
    if (tid == 0) hs2[0] = (c == 0) ? y0[b] : dec[b * TT + t0 - 1];

    float fga[NQ], fgb[NQ];
#pragma unroll
    for (int q = 0; q < NQ; ++q) {
        int n = q * 512 + tid;
        if (n < N_MESH) {
            float2 mv = *(const float2*)&mesh[2 * n];
            fgb[q] = rintf(mv.x * 100.0f);
            fga[q] = rintf(mv.y * 100.0f);
        } else { fga[q] = 0.f; fgb[q] = 0.f; }
    }
    __syncthreads();
    build_params(tid, hs2, tp);
    __syncthreads();

    float P[NQ], R[NQ];
    float sg0 = tp[0].w;
#pragma unroll
    for (int q = 0; q < NQ; ++q) { P[q] = 1.f; R[q] = -sg0; }

    for (int tb = 0; tb < CHUNK; tb += 8) {
#pragma unroll
        for (int j = 0; j < 8; ++j) {
            float4 p = tp[tb + j];
            bool inc = p.y > 0.f;
            bool dl0 = p.x == 0.f;
            if (inc) {
                if (dl0) {
#pragma unroll
                    for (int q = 0; q < NQ; ++q) {
                        float A = __builtin_amdgcn_fmed3f(fga[q] + p.z, 0.f, 1.f);
                        P[q] *= A;
                        R[q] *= A;
                    }
                } else {
#pragma unroll
                    for (int q = 0; q < NQ; ++q) {
                        float A = __builtin_amdgcn_fmed3f(fga[q] + p.z, 0.f, 1.f);
                        P[q] *= A;
                        R[q] = (R[q] + p.x) * A;
                    }
                }
            } else {
                if (dl0) {
#pragma unroll
                    for (int q = 0; q < NQ; ++q) {
                        float A = __builtin_amdgcn_fmed3f(p.z - fgb[q], 0.f, 1.f);
                        P[q] *= A;
                        R[q] *= A;
                    }
                } else {
#pragma unroll
                    for (int q = 0; q < NQ; ++q) {
                        float A = __builtin_amdgcn_fmed3f(p.z - fgb[q], 0.f, 1.f);
                        P[q] *= A;
                        R[q] = (R[q] + p.x) * A;
                    }
                }
            }
        }
    }
    float sgl = tp[CHUNK - 1].w;
    size_t basew = ((size_t)(c * NB + b)) * NPAD;
#pragma unroll
    for (int q = 0; q < NQ; ++q) {
        float2 v; v.x = P[q]; v.y = R[q] + sgl;
        PQ[basew + q * 512 + tid] = v;
    }
}

// ---------------------------------------------------------------------------
// k2: blocks [0,81) = MFMA density MLP (proven body); [81,169) = phase2.
// ---------------------------------------------------------------------------
__global__ __launch_bounds__(512) void k2_mlp_phase2(
    const float* __restrict__ mesh, const float* __restrict__ Win,
    const float* __restrict__ bin,  const half8* __restrict__ WT,
    const float* __restrict__ bblk, const float* __restrict__ Wout,
    const float* __restrict__ bout, float* __restrict__ density,
    const float* __restrict__ s0_in, const float2* __restrict__ PQ,
    float* __restrict__ Sarr)
{
    __shared__ __align__(16) char hA[64 * 512];   // 32 KB
    __shared__ float psum[4][16][2];
    const int tid  = threadIdx.x;

    if (blockIdx.x >= MLP_NBLK) {
        // ---- phase2: boundary states into dense Sarr ----
        int idx = blockIdx.x - MLP_NBLK;   // 0..87
        int nbb = idx % NQ;
        int b   = idx / NQ;
        int n   = nbb * 512 + tid;
        float s = (n < N_MESH) ? s0_in[b * N_MESH + n] : 0.f;
#pragma unroll 4
        for (int c = 0; c < NCHUNK; ++c) {
            size_t ix = ((size_t)(c * NB + b)) * NPAD + n;
            float2 pv = PQ[ix];
            Sarr[ix] = s;
            s = fmaf(pv.x, s, pv.y);
        }
        return;
    }

    const int w    = tid >> 6;
    const int lane = tid & 63;
    const int rl   = lane & 15;
    const int cg   = lane >> 4;
    const int mt   = w & 3;
    const int nh   = w >> 2;
    const int row0 = blockIdx.x * 64;

    float hreg[8][4];

    {
        float m0[4], m1[4];
#pragma unroll
        for (int r = 0; r < 4; ++r) {
            int gr = row0 + mt * 16 + cg * 4 + r;
            if (gr < N_MESH) { m0[r] = mesh[2 * gr]; m1[r] = mesh[2 * gr + 1]; }
            else { m0[r] = 0.f; m1[r] = 0.f; }
        }
#pragma unroll
        for (int j = 0; j < 8; ++j) {
            int col = nh * 128 + j * 16 + rl;
            float wa = Win[col], wb = Win[HID + col], bi = bin[col];
#pragma unroll
            for (int r = 0; r < 4; ++r) {
                float v = fmaxf(fmaf(m0[r], wa, fmaf(m1[r], wb, bi)), 0.f);
                hreg[j][r] = v;
                *(_Float16*)(hA + swz(mt * 16 + cg * 4 + r, col * 2)) =
                    (_Float16)v;
            }
        }
    }
    __syncthreads();

    for (int L = 0; L < NLAYERS; ++L) {
        half8 af[8];
#pragma unroll
        for (int kg = 0; kg < 8; ++kg)
            af[kg] = *(const half8*)(hA + swz(mt * 16 + rl, kg * 64 + cg * 16));
        __syncthreads();

        float bias[8];
#pragma unroll
        for (int j = 0; j < 8; ++j)
            bias[j] = bblk[L * HID + nh * 128 + j * 16 + rl];

        f32x4 acc[8];
#pragma unroll
        for (int j = 0; j < 8; ++j) acc[j] = (f32x4){0.f, 0.f, 0.f, 0.f};

        const half8* WTL = WT + ((size_t)(L * 8) * 16 + nh * 8) * 64 + lane;
        half8 b0[8], b1[8];
#pragma unroll
        for (int j = 0; j < 8; ++j) b0[j] = WTL[(size_t)j * 64];
#pragma unroll
        for (int kg2 = 0; kg2 < 8; kg2 += 2) {
#pragma unroll
            for (int j = 0; j < 8; ++j)
                b1[j] = WTL[(size_t)(kg2 + 1) * 1024 + (size_t)j * 64];
#pragma unroll
            for (int j = 0; j < 8; ++j)
                acc[j] = __builtin_amdgcn_mfma_f32_16x16x32_f16(
                    af[kg2], b0[j], acc[j], 0, 0, 0);
            if (kg2 + 2 < 8) {
#pragma unroll
                for (int j = 0; j < 8; ++j)
                    b0[j] = WTL[(size_t)(kg2 + 2) * 1024 + (size_t)j * 64];
            }
#pragma unroll
            for (int j = 0; j < 8; ++j)
                acc[j] = __builtin_amdgcn_mfma_f32_16x16x32_f16(
                    af[kg2 + 1], b1[j], acc[j], 0, 0, 0);
        }

#pragma unroll
        for (int j = 0; j < 8; ++j) {
            int col = nh * 128 + j * 16 + rl;
#pragma unroll
            for (int r = 0; r < 4; ++r) {
                float v = hreg[j][r] + fmaxf(acc[j][r] + bias[j], 0.f);
                hreg[j][r] = v;
                if (L < NLAYERS - 1)
                    *(_Float16*)(hA + swz(mt * 16 + cg * 4 + r, col * 2)) =
                        (_Float16)v;
            }
        }
        if (L < NLAYERS - 1) __syncthreads();
    }

    {
        float p[4] = {0.f, 0.f, 0.f, 0.f};
#pragma unroll
        for (int j = 0; j < 8; ++j) {
            float wo = Wout[nh * 128 + j * 16 + rl];
#pragma unroll
            for (int r = 0; r < 4; ++r) p[r] = fmaf(hreg[j][r], wo, p[r]);
        }
#pragma unroll
        for (int st = 1; st < 16; st <<= 1)
#pragma unroll
            for (int r = 0; r < 4; ++r) p[r] += __shfl_xor(p[r], st, 64);
        if (rl == 0) {
#pragma unroll
            for (int r = 0; r < 4; ++r) psum[mt][cg * 4 + r][nh] = p[r];
        }
    }
    __syncthreads();
    if (tid < 64) {
        int gr = row0 + tid;
        float pp = psum[tid >> 4][tid & 15][0] + psum[tid >> 4][tid & 15][1];
        if (gr < N_MESH) density[gr] = sigmoid_fast(pp + bout[0]);
    }
}

// ---------------------------------------------------------------------------
// k3: blocks [0,512) phase3 + in-block finalize; [512,533) density_b copy.
// ---------------------------------------------------------------------------
__global__ __launch_bounds__(512, 4) void k3_phase3_fin(
    const float* __restrict__ dec, const float* __restrict__ y0,
    const float* __restrict__ mesh, const float* __restrict__ density,
    const float* __restrict__ Sarr, float* __restrict__ out)
{
    __shared__ __align__(16) char smem[SMEM3];
    const int tid = threadIdx.x;
    const int bid = blockIdx.x;

    if (bid >= SCAN_GRID) {
        // ---- density_b copy ----
        int idx = bid - SCAN_GRID;
#pragma unroll
        for (int k = 0; k < 4; ++k) {
            int j = idx * 2048 + k * 512 + tid;
            if (j < NB * N_MESH) out[OUT_DENSB + j] = density[j % N_MESH];
        }
        return;
    }

    float* hs2 = (float*)smem;
    float4* tp = (float4*)(smem + OFF_TP);
    float* red  = (float*)(smem + OFF_RED);    // [32 t][36]
    float* Dred = (float*)(smem + OFF_DRED);   // [32]

    const int b = bid & 7;
    const int c = bid >> 3;
    const int t0 = c * CHUNK;

    if (tid < CHUNK) hs2[tid + 1] = dec[b * TT + t0 + tid];
    if (tid == 0) hs2[0] = (c == 0) ? y0[b] : dec[b * TT + t0 - 1];

    float fga[NQ], fgb[NQ];
    float d[NQ], S[NQ];
#pragma unroll
    for (int q = 0; q < NQ; ++q) {
        int n = q * 512 + tid;
        if (n < N_MESH) {
            float2 mv = *(const float2*)&mesh[2 * n];
            fgb[q] = rintf(mv.x * 100.0f);
            fga[q] = rintf(mv.y * 100.0f);
            d[q]  = density[n];
            S[q]  = Sarr[((size_t)(c * NB + b)) * NPAD + n];
        } else { fga[q] = 0.f; fgb[q] = 0.f; d[q] = 0.f; S[q] = 0.f; }
    }
    // block-local D = sum(density) (identical order in every block)
    {
        float Dp = 0.f;
#pragma unroll
        for (int q = 0; q < NQ; ++q) Dp += d[q];
        Dp = dpp16_sum(Dp);
        if ((tid & 15) == 0) Dred[tid >> 4] = Dp;
    }
    __syncthreads();
    build_params(tid, hs2, tp);
    __syncthreads();

    float z[NQ];
    float sg0 = tp[0].w;
#pragma unroll
    for (int q = 0; q < NQ; ++q) z[q] = S[q] - sg0;

    for (int tb = 0; tb < CHUNK; tb += 8) {
        float v[8];
#pragma unroll
        for (int j = 0; j < 8; ++j) {
            float4 p = tp[tb + j];
            bool inc = p.y > 0.f;
            bool dl0 = p.x == 0.f;
            float a0 = 0.f, a1 = 0.f;
            if (inc) {
                if (dl0) {
#pragma unroll
                    for (int q = 0; q < NQ; ++q) {
                        float A = __builtin_amdgcn_fmed3f(fga[q] + p.z, 0.f, 1.f);
                        float zn = z[q] * A;
                        z[q] = zn;
                        if (q & 1) a1 = fmaf(d[q], zn, a1);
                        else       a0 = fmaf(d[q], zn, a0);
                    }
                } else {
#pragma unroll
                    for (int q = 0; q < NQ; ++q) {
                        float A = __builtin_amdgcn_fmed3f(fga[q] + p.z, 0.f, 1.f);
                        float zn = (z[q] + p.x) * A;
                        z[q] = zn;
                        if (q & 1) a1 = fmaf(d[q], zn, a1);
                        else       a0 = fmaf(d[q], zn, a0);
                    }
                }
            } else {
                if (dl0) {
#pragma unroll
                    for (int q = 0; q < NQ; ++q) {
                        float A = __builtin_amdgcn_fmed3f(p.z - fgb[q], 0.f, 1.f);
                        float zn = z[q] * A;
                        z[q] = zn;
                        if (q & 1) a1 = fmaf(d[q], zn, a1);
                        else       a0 = fmaf(d[q], zn, a0);
                    }
                } else {
#pragma unroll
                    for (int q = 0; q < NQ; ++q) {
                        float A = __builtin_amdgcn_fmed3f(p.z - fgb[q], 0.f, 1.f);
                        float zn = (z[q] + p.x) * A;
                        z[q] = zn;
                        if (q & 1) a1 = fmaf(d[q], zn, a1);
                        else       a0 = fmaf(d[q], zn, a0);
                    }
                }
            }
            v[j] = a0 + a1;
        }
#pragma unroll
        for (int j = 0; j < 8; ++j) v[j] = dpp16_sum(v[j]);
        float outv = v[0];
#pragma unroll
        for (int j = 1; j < 8; ++j) if ((tid & 15) == j) outv = v[j];
        if ((tid & 15) < 8)
            red[(tb + (tid & 15)) * 36 + (tid >> 4)] = outv;
    }
    __syncthreads();

    // finalize: 32 threads, one per t in this chunk
    if (tid < CHUNK) {
        float acc = 0.f;
#pragma unroll
        for (int g4 = 0; g4 < 32; g4 += 4) {
            float4 r4 = *(const float4*)&red[tid * 36 + g4];
            acc += (r4.x + r4.y) + (r4.z + r4.w);
        }
        float D = 0.f;
#pragma unroll
        for (int g4 = 0; g4 < 32; g4 += 4) {
            float4 d4 = *(const float4*)&Dred[g4];
            D += (d4.x + d4.y) + (d4.z + d4.w);
        }
        float gd = tp[tid].w;                // direction sign at t
        int t = t0 + tid;
        float m = (acc + gd * D) / D;
        out[OUT_M + b * TT + t] = m;
        out[OUT_BNORM + b * TT + t] = 0.5f * m + 0.5f;
    }
}

extern "C" void kernel_launch(void* const* d_in, const int* in_sizes, int n_in,
                              void* d_out, int out_size, void* d_ws, size_t ws_size,
                              hipStream_t stream) {
    const float* dec  = (const float*)d_in[1];
    const float* s0   = (const float*)d_in[2];
    const float* y0   = (const float*)d_in[3];
    const float* mesh = (const float*)d_in[4];
    const float* Win  = (const float*)d_in[5];
    const float* bin  = (const float*)d_in[6];
    const float* Wblk = (const float*)d_in[7];
    const float* bblk = (const float*)d_in[8];
    const float* Wout = (const float*)d_in[9];
    const float* bout = (const float*)d_in[10];
    float* out = (float*)d_out;
    float* ws  = (float*)d_ws;

    float*  density  = ws + WS_DENSITY;
    half8*  wt       = (half8*)(ws + WS_WT);
    float*  pqf      = ws + WS_PQ;
    float2* pq       = (float2*)pqf;
    float*  sarr     = ws + WS_S;

    k1_scan1_prep<<<SCAN_GRID + PREP_NBLK + COPY_NBLK, 512, 0, stream>>>(
        dec, y0, mesh, Wblk, pq, wt, s0, out);
    k2_mlp_phase2<<<MLP_NBLK + PH2_NBLK, 512, 0, stream>>>(
        mesh, Win, bin, wt, bblk, Wout, bout, density, s0, pq, sarr);
    k3_phase3_fin<<<SCAN_GRID + DENSB_NBLK, 512, 0, stream>>>(
        dec, y0, mesh, density, sarr, out);
}